// Round 15
// baseline (1742.084 us; speedup 1.0000x reference)
//
#include <hip/hip_runtime.h>
#include <stdint.h>

#define LCOUNT 6
#define BB 4
#define SS 2048
#define DD 512
#define HH 8
#define DKK 64
#define FFDIM 2048
#define MM (BB*SS)  // 8192 rows

typedef __attribute__((ext_vector_type(8))) __bf16 bf16x8;
typedef __attribute__((ext_vector_type(4))) float f32x4;
typedef unsigned short u16;

__device__ __forceinline__ u16 f2bf(float f) {
  union { __bf16 h; u16 u; } v; v.h = (__bf16)f; return v.u;
}
__device__ __forceinline__ float bf2f(u16 u) {
  union { uint32_t u; float f; } v; v.u = ((uint32_t)u) << 16;
  return v.f;
}

__device__ __forceinline__ void gload_lds16(const u16* gsrc, u16* ldst) {
  __builtin_amdgcn_global_load_lds((const __attribute__((address_space(1))) char*)gsrc,
                                   (__attribute__((address_space(3))) char*)ldst, 16, 0, 0);
}

// ---------------------------------------------------------------------------
// prep: blocks <4096 convert x/enc fp32->bf16; blocks >=4096 concat biases.
__global__ __launch_bounds__(256)
void prep(const float* __restrict__ x, const float* __restrict__ enc,
          u16* __restrict__ Hb, u16* __restrict__ Eb,
          const float* a0, const float* a1, const float* a2,
          const float* c0, const float* c1, const float* c2,
          float* dqkv, float* dca) {
  if (blockIdx.x < 4096) {
    int i = (blockIdx.x * 256 + threadIdx.x) * 8;
    const int half = MM * 512;
    const float* src = (i < half) ? x : enc;
    u16* dst = (i < half) ? Hb : Eb;
    int j = (i < half) ? i : i - half;
    float4 a = *(const float4*)&src[j];
    float4 b = *(const float4*)&src[j + 4];
    union { u16 us[8]; uint4 v; } pk;
    pk.us[0] = f2bf(a.x); pk.us[1] = f2bf(a.y); pk.us[2] = f2bf(a.z); pk.us[3] = f2bf(a.w);
    pk.us[4] = f2bf(b.x); pk.us[5] = f2bf(b.y); pk.us[6] = f2bf(b.z); pk.us[7] = f2bf(b.w);
    *(uint4*)&dst[j] = pk.v;
  } else {
    int i = (blockIdx.x - 4096) * 256 + threadIdx.x;
    const int half = LCOUNT * 1536;
    if (i >= 2 * half) return;
    bool ca = i >= half;
    int j = ca ? i - half : i;
    int l = j / 1536, cc = j % 1536;
    const float* s = cc < 512 ? (ca ? c0 : a0) : cc < 1024 ? (ca ? c1 : a1) : (ca ? c2 : a2);
    (ca ? dca : dqkv)[j] = s[l * 512 + (cc & 511)];
  }
}

// ---------------------------------------------------------------------------
// Batched 512x512 weight transpose: 8 slots x 6 layers in one dispatch.
struct WtBatch {
  const float* src[8];
  u16* dst[8];
  unsigned long long lstr[8];
};
__global__ __launch_bounds__(256) void wtrans8(WtBatch wb) {
  __shared__ float tile[64 * 65];
  const int z = blockIdx.z;
  const int slot = z / 6, l = z - slot * 6;
  const float* Wl = wb.src[slot] + (size_t)l * 512 * 512;
  u16* Wtl = wb.dst[slot] + (size_t)l * wb.lstr[slot];
  const int n0 = blockIdx.x * 64, k0 = blockIdx.y * 64;
  const int tid = threadIdx.x;
  const int r = tid >> 2, c4 = (tid & 3) * 16;
#pragma unroll
  for (int j = 0; j < 16; j += 4) {
    float4 v = *(const float4*)&Wl[(size_t)(k0 + r) * 512 + n0 + c4 + j];
    tile[r * 65 + c4 + j + 0] = v.x;
    tile[r * 65 + c4 + j + 1] = v.y;
    tile[r * 65 + c4 + j + 2] = v.z;
    tile[r * 65 + c4 + j + 3] = v.w;
  }
  __syncthreads();
  const int nr = tid >> 2, kc = (tid & 3) * 16;
#pragma unroll
  for (int half = 0; half < 2; ++half) {
    union { u16 us[8]; uint4 v; } pk;
#pragma unroll
    for (int e = 0; e < 8; ++e) pk.us[e] = f2bf(tile[(kc + half * 8 + e) * 65 + nr]);
    *(uint4*)&Wtl[(size_t)(n0 + nr) * 512 + k0 + kc + half * 8] = pk.v;
  }
}

// ---------------------------------------------------------------------------
// FFN weight transposes (w1: 512->2048, w2: 2048->512), 12 z-slices.
__global__ __launch_bounds__(256)
void wtrans_ffn(const float* __restrict__ w1, const float* __restrict__ w2,
                u16* __restrict__ w1t, u16* __restrict__ w2t) {
  __shared__ float tile[64 * 65];
  const int z = blockIdx.y;
  const bool is2 = z >= 6;
  const int l = is2 ? z - 6 : z;
  const float* Wl = (is2 ? w2 : w1) + (size_t)l * 512 * 2048;
  u16* Wtl = (is2 ? w2t : w1t) + (size_t)l * 512 * 2048;
  const int K_ = is2 ? 2048 : 512, N_ = is2 ? 512 : 2048;
  const int bx = blockIdx.x;
  const int n0 = is2 ? (bx & 7) * 64 : (bx & 31) * 64;
  const int k0 = is2 ? (bx >> 3) * 64 : (bx >> 5) * 64;
  const int tid = threadIdx.x;
  const int r = tid >> 2, c4 = (tid & 3) * 16;
#pragma unroll
  for (int j = 0; j < 16; j += 4) {
    float4 v = *(const float4*)&Wl[(size_t)(k0 + r) * N_ + n0 + c4 + j];
    tile[r * 65 + c4 + j + 0] = v.x;
    tile[r * 65 + c4 + j + 1] = v.y;
    tile[r * 65 + c4 + j + 2] = v.z;
    tile[r * 65 + c4 + j + 3] = v.w;
  }
  __syncthreads();
  const int nr = tid >> 2, kc = (tid & 3) * 16;
#pragma unroll
  for (int half = 0; half < 2; ++half) {
    union { u16 us[8]; uint4 v; } pk;
#pragma unroll
    for (int e = 0; e < 8; ++e) pk.us[e] = f2bf(tile[(kc + half * 8 + e) * 65 + nr]);
    *(uint4*)&Wtl[(size_t)(n0 + nr) * K_ + k0 + kc + half * 8] = pk.v;
  }
}

// ---------------------------------------------------------------------------
// GEMM: C[M,N] = A[M,K] @ W[K,N] + bias; Wt[N][K]; C row stride CS.
// Template BMT/BNT/BKT; 2x2 waves. Dual-A (bcol >= a2col reads A2). RES:
// epilogue adds residual resid[rowg*DD+col] (FFN2 path). XCD-aware chunked
// swizzle. VT: cols >= vtc0 -> Vt transposed.
template <int BMT, int BNT, int BKT, bool RELU, bool VT, bool RES>
__global__ __launch_bounds__(256)
void gemm_bt(const u16* __restrict__ A, const u16* __restrict__ Bt,
             const float* __restrict__ bias, u16* __restrict__ C,
             int N_, int K_, int CS, u16* __restrict__ vt, int vtc0,
             const u16* __restrict__ A2, int a2col,
             const u16* __restrict__ resid) {
  constexpr int MR = BMT / 32;
  constexpr int NR = BNT / 32;
  constexpr int CH = BKT / 8;
  constexpr int RPR = 2048 / BKT;
  constexpr int KS = BKT / 32;
  __shared__ u16 As[BMT * BKT];
  __shared__ u16 Bs[BNT * BKT];
  const int tid = threadIdx.x;
  const int wid = tid >> 6, lane = tid & 63;
  const int l15 = lane & 15, g = lane >> 4;
  const int wr = wid >> 1, wc = wid & 1;
  const int lrow = (CH == 8) ? (lane >> 3) : (lane >> 4);
  const int lch  = lane & (CH - 1);
  const int wrows = 64 / CH;
  const int lin = blockIdx.x + gridDim.x * blockIdx.y;
  const int nwg = gridDim.x * gridDim.y;
  const int swz = (lin & 7) * (nwg >> 3) + (lin >> 3);
  const int brow = (swz / gridDim.x) * BMT;
  const int bcol = (swz % gridDim.x) * BNT;
  const u16* Ap = (A2 != nullptr && bcol >= a2col) ? A2 : A;

  f32x4 acc[MR][NR];
#pragma unroll
  for (int m = 0; m < MR; ++m)
#pragma unroll
    for (int n = 0; n < NR; ++n) acc[m][n] = (f32x4){0.f, 0.f, 0.f, 0.f};

  for (int kt = 0; kt < K_; kt += BKT) {
#pragma unroll
    for (int r = 0; r < BMT / RPR; ++r) {
      int row = r * RPR + wid * wrows + lrow;
      int slot = lch ^ (row & 7);
      gload_lds16(Ap + (size_t)(brow + row) * K_ + kt + slot * 8,
                  &As[r * 2048 + wid * 512]);
    }
#pragma unroll
    for (int r = 0; r < BNT / RPR; ++r) {
      int row = r * RPR + wid * wrows + lrow;
      int slot = lch ^ (row & 7);
      gload_lds16(Bt + (size_t)(bcol + row) * K_ + kt + slot * 8,
                  &Bs[r * 2048 + wid * 512]);
    }
    __syncthreads();
#pragma unroll
    for (int ks = 0; ks < KS; ++ks) {
      bf16x8 af[MR], bfr[NR];
#pragma unroll
      for (int m = 0; m < MR; ++m) {
        int row = wr * (BMT / 2) + m * 16 + l15;
        int slot = (ks * 4 + g) ^ (row & 7);
        af[m] = *(const bf16x8*)&As[row * BKT + slot * 8];
      }
#pragma unroll
      for (int n = 0; n < NR; ++n) {
        int row = wc * (BNT / 2) + n * 16 + l15;
        int slot = (ks * 4 + g) ^ (row & 7);
        bfr[n] = *(const bf16x8*)&Bs[row * BKT + slot * 8];
      }
#pragma unroll
      for (int m = 0; m < MR; ++m)
#pragma unroll
        for (int n = 0; n < NR; ++n)
          acc[m][n] = __builtin_amdgcn_mfma_f32_16x16x32_bf16(af[m], bfr[n], acc[m][n], 0, 0, 0);
    }
    __syncthreads();
  }
#pragma unroll
  for (int n = 0; n < NR; ++n) {
    int col = bcol + wc * (BNT / 2) + n * 16 + l15;
    float bv = bias ? bias[col] : 0.f;
    if (VT && col >= vtc0) {
      int hh = (col - vtc0) >> 6, dd = (col - vtc0) & 63;
#pragma unroll
      for (int m = 0; m < MR; ++m) {
        int s0g = brow + wr * (BMT / 2) + m * 16 + g * 4;
        int bb = s0g >> 11, ss = s0g & (SS - 1);
        union { u16 us[4]; uint2 v; } pk;
#pragma unroll
        for (int r = 0; r < 4; ++r) pk.us[r] = f2bf(acc[m][n][r] + bv);
        *(uint2*)&vt[(((size_t)(bb * HH + hh)) * DKK + dd) * SS + ss] = pk.v;
      }
    } else {
#pragma unroll
      for (int m = 0; m < MR; ++m) {
#pragma unroll
        for (int r = 0; r < 4; ++r) {
          int rowg = brow + wr * (BMT / 2) + m * 16 + g * 4 + r;
          float v = acc[m][n][r] + bv;
          if (RES) v += bf2f(resid[(size_t)rowg * DD + col]);
          if (RELU) v = fmaxf(v, 0.f);
          C[(size_t)rowg * CS + col] = f2bf(v);
        }
      }
    }
  }
}

// ---------------------------------------------------------------------------
// Fused GEMM + residual + LayerNorm (K=512 only).
__global__ __launch_bounds__(256)
void gemm_ln(const u16* __restrict__ A, const u16* __restrict__ Bt,
             const float* __restrict__ bias, const u16* __restrict__ Res,
             const float* __restrict__ gamma, const float* __restrict__ beta,
             u16* __restrict__ Out, float* __restrict__ Ofp, int K_) {
  __shared__ u16 As[16 * 64];
  __shared__ u16 Bs[512 * 64];
  __shared__ float red[4][16][2];
  const int tid = threadIdx.x;
  const int wid = tid >> 6, lane = tid & 63;
  const int l15 = lane & 15, g = lane >> 4;
  const int lin = blockIdx.x;
  const int swz = (lin & 7) * (gridDim.x >> 3) + (lin >> 3);
  const int brow = swz * 16;
  const int lrow8 = lane >> 3, lch = lane & 7;

  f32x4 acc[8];
#pragma unroll
  for (int n = 0; n < 8; ++n) acc[n] = (f32x4){0.f, 0.f, 0.f, 0.f};

  for (int kt = 0; kt < K_; kt += 64) {
#pragma unroll
    for (int r = 0; r < 17; ++r) {
      int u = wid + 4 * r;
      if (u < 66) {
        if (u < 2) {
          int row = u * 8 + lrow8;
          int slot = lch ^ (row & 7);
          gload_lds16(A + (size_t)(brow + row) * K_ + kt + slot * 8, &As[u * 512]);
        } else {
          int row = (u - 2) * 8 + lrow8;
          int slot = lch ^ (row & 7);
          gload_lds16(Bt + (size_t)row * K_ + kt + slot * 8, &Bs[(u - 2) * 512]);
        }
      }
    }
    __syncthreads();
#pragma unroll
    for (int ks = 0; ks < 2; ++ks) {
      bf16x8 af = *(const bf16x8*)&As[l15 * 64 + (((ks * 4 + g) ^ (l15 & 7)) * 8)];
#pragma unroll
      for (int n = 0; n < 8; ++n) {
        int c = wid * 128 + n * 16 + l15;
        bf16x8 bfr = *(const bf16x8*)&Bs[c * 64 + (((ks * 4 + g) ^ (c & 7)) * 8)];
        acc[n] = __builtin_amdgcn_mfma_f32_16x16x32_bf16(af, bfr, acc[n], 0, 0, 0);
      }
    }
    __syncthreads();
  }
#pragma unroll
  for (int rd = 0; rd < 4; ++rd) {
    int off = rd * 2048 + tid * 8;
    int row = off >> 9, col = off & 511;
    uint4 v = *(const uint4*)&Res[(size_t)(brow + row) * DD + col];
    *(uint4*)&Bs[row * 520 + col] = v;
  }
  __syncthreads();
  float z[8][4];
  float s[4] = {0.f, 0.f, 0.f, 0.f}, s2[4] = {0.f, 0.f, 0.f, 0.f};
#pragma unroll
  for (int n = 0; n < 8; ++n) {
    int col = wid * 128 + n * 16 + l15;
    float bv = bias[col];
#pragma unroll
    for (int r = 0; r < 4; ++r) {
      int rl = g * 4 + r;
      float x = acc[n][r] + bv + bf2f(Bs[rl * 520 + col]);
      z[n][r] = x; s[r] += x; s2[r] += x * x;
    }
  }
#pragma unroll
  for (int r = 0; r < 4; ++r) {
    s[r] += __shfl_xor(s[r], 1);  s2[r] += __shfl_xor(s2[r], 1);
    s[r] += __shfl_xor(s[r], 2);  s2[r] += __shfl_xor(s2[r], 2);
    s[r] += __shfl_xor(s[r], 4);  s2[r] += __shfl_xor(s2[r], 4);
    s[r] += __shfl_xor(s[r], 8);  s2[r] += __shfl_xor(s2[r], 8);
  }
  if (l15 == 0) {
#pragma unroll
    for (int r = 0; r < 4; ++r) {
      red[wid][g * 4 + r][0] = s[r];
      red[wid][g * 4 + r][1] = s2[r];
    }
  }
  __syncthreads();
  float mean[4], rs[4];
#pragma unroll
  for (int r = 0; r < 4; ++r) {
    int rl = g * 4 + r;
    float ts  = red[0][rl][0] + red[1][rl][0] + red[2][rl][0] + red[3][rl][0];
    float ts2 = red[0][rl][1] + red[1][rl][1] + red[2][rl][1] + red[3][rl][1];
    float mn = ts * (1.f / 512.f);
    float var = ts2 * (1.f / 512.f) - mn * mn;
    mean[r] = mn; rs[r] = rsqrtf(var + 1e-5f);
  }
#pragma unroll
  for (int n = 0; n < 8; ++n) {
    int col = wid * 128 + n * 16 + l15;
    float gm = gamma[col], bt = beta[col];
#pragma unroll
    for (int r = 0; r < 4; ++r) {
      int rowg = brow + g * 4 + r;
      float o = (z[n][r] - mean[r]) * rs[r] * gm + bt;
      Out[(size_t)rowg * DD + col] = f2bf(o);
      if (Ofp) Ofp[(size_t)rowg * DD + col] = o;
    }
  }
}

// ---------------------------------------------------------------------------
// LayerNorm(a) * g + beta (residual already folded into a); one wave per row.
__global__ __launch_bounds__(256)
void ln_kernel(const u16* __restrict__ A,
               const float* __restrict__ gamma, const float* __restrict__ beta,
               u16* __restrict__ out_bf, float* __restrict__ out_f32) {
  const int row = blockIdx.x * 4 + (threadIdx.x >> 6);
  const int lane = threadIdx.x & 63;
  uint4 av = *(const uint4*)&A[(size_t)row * DD + lane * 8];
  const u16* au = (const u16*)&av;
  float z[8], s = 0.f, s2 = 0.f;
#pragma unroll
  for (int j = 0; j < 8; ++j) {
    float x = bf2f(au[j]);
    z[j] = x; s += x; s2 += x * x;
  }
#pragma unroll
  for (int off = 1; off < 64; off <<= 1) {
    s += __shfl_xor(s, off);
    s2 += __shfl_xor(s2, off);
  }
  float mean = s * (1.f / 512.f);
  float var = s2 * (1.f / 512.f) - mean * mean;
  float rs = rsqrtf(var + 1e-5f);
  union { u16 us[8]; uint4 v; } pk;
#pragma unroll
  for (int j = 0; j < 8; ++j) {
    float o = (z[j] - mean) * rs * gamma[lane * 8 + j] + beta[lane * 8 + j];
    pk.us[j] = f2bf(o);
    if (out_f32) out_f32[(size_t)row * DD + lane * 8 + j] = o;
  }
  *(uint4*)&out_bf[(size_t)row * DD + lane * 8] = pk.v;
}

// ---------------------------------------------------------------------------
// Flash attention, swapped-QK^T (r6/r9 schedule). Grid 1024, XCD-clustered;
// causal balance interleave. K/V LDS-staged (global_load_lds, dbuf, one
// barrier/tile). Ps shrunk to 16x32/wave (4KB total) by splitting P-pack/PV
// into two k-halves -> LDS 36864 B -> 4 blocks/CU (was 3: 4x40960 = full
// 160KiB collided with reserved LDS). 16B-slot swizzle sl=(lc>>1)^((l15>>1)&3)
// gives 2-way (free) on both write and read.
template <bool CAUSAL>
__global__ __launch_bounds__(256, 4)
void attn_kernel(const u16* __restrict__ Qm, const u16* __restrict__ Km,
                 const u16* __restrict__ Vt, u16* __restrict__ Om, int qks) {
  __shared__ u16 Ks[2][64 * 64];
  __shared__ u16 Vs[2][64 * 64];
  __shared__ u16 Ps[4][16 * 32];
  const int lin = blockIdx.x;
  const int bh = (lin & 7) * 4 + ((lin >> 3) >> 5);
  const int qc = (lin >> 3) & 31;
  const int qb = (qc & 1) ? (31 - (qc >> 1)) : (qc >> 1);
  const int h = bh & 7, b = bh >> 3;
  const int tid = threadIdx.x, wid = tid >> 6, lane = tid & 63;
  const int l15 = lane & 15, g = lane >> 4;
  const int qstart = qb * 64;
  const size_t qbase = ((size_t)b * SS) * qks + h * DKK;
  const size_t vtbase = (size_t)(b * HH + h) * DKK * SS;
  const size_t obase = ((size_t)b * SS) * DD + h * DKK;
  u16* psw = &Ps[wid][0];
  const int srow = wid * 8 + (lane >> 3);
  const int sslot = lane & 7;
  const int qg = qstart + wid * 16 + l15;
  const int psl = (l15 >> 1) & 3;           // Ps 16B-slot XOR
  const float SC = 0.18033688f;  // 0.125 * log2(e)

  const u16* kp = Km + qbase;
  const u16* vp = Vt + vtbase;

  bf16x8 qf[2];
#pragma unroll
  for (int ks = 0; ks < 2; ++ks)
    qf[ks] = *(const bf16x8*)&Qm[qbase + (size_t)qg * qks + ks * 32 + g * 8];

  f32x4 oacc[4];
#pragma unroll
  for (int nb = 0; nb < 4; ++nb) oacc[nb] = (f32x4){0.f, 0.f, 0.f, 0.f};
  float m_run = -3.0e38f, l_run = 0.f;

  const int T = CAUSAL ? (qb + 1) : (SS / 64);

#pragma unroll
  for (int r = 0; r < 2; ++r) {
    int row = r * 32 + srow;
    int slot = sslot ^ (row & 7);
    gload_lds16(kp + (size_t)row * qks + slot * 8, &Ks[0][r * 2048 + wid * 512]);
    gload_lds16(vp + (size_t)row * SS + slot * 8, &Vs[0][r * 2048 + wid * 512]);
  }
  __syncthreads();

  int cur = 0;
  for (int t = 0; t < T; ++t) {
    const int kstart = t * 64;
    if (t + 1 < T) {
#pragma unroll
      for (int r = 0; r < 2; ++r) {
        int row = r * 32 + srow;
        int slot = sslot ^ (row & 7);
        gload_lds16(kp + (size_t)(kstart + 64 + row) * qks + slot * 8,
                    &Ks[cur ^ 1][r * 2048 + wid * 512]);
        gload_lds16(vp + (size_t)row * SS + kstart + 64 + slot * 8,
                    &Vs[cur ^ 1][r * 2048 + wid * 512]);
      }
    }
    // ---- QK^T swapped: sacc[nb][r] = S_raw[k=kstart+nb*16+g*4+r][q=qg] ----
    f32x4 sacc[4];
#pragma unroll
    for (int nb = 0; nb < 4; ++nb) sacc[nb] = (f32x4){0.f, 0.f, 0.f, 0.f};
    __builtin_amdgcn_s_setprio(1);
#pragma unroll
    for (int nb = 0; nb < 4; ++nb) {
      int row = nb * 16 + l15;
#pragma unroll
      for (int ks = 0; ks < 2; ++ks) {
        bf16x8 kf = *(const bf16x8*)&Ks[cur][row * 64 + (((ks * 4 + g) ^ (row & 7)) * 8)];
        sacc[nb] = __builtin_amdgcn_mfma_f32_16x16x32_bf16(kf, qf[ks], sacc[nb], 0, 0, 0);
      }
    }
    __builtin_amdgcn_s_setprio(0);
    // ---- causal mask (diagonal tile only) ----
    if (CAUSAL && t == T - 1) {
#pragma unroll
      for (int nb = 0; nb < 4; ++nb)
#pragma unroll
        for (int r = 0; r < 4; ++r)
          if ((kstart + nb * 16 + g * 4 + r) > qg) sacc[nb][r] = -3.0e38f;
    }
    // ---- online softmax, scale folded into SC ----
    f32x4 m4 = sacc[0];
#pragma unroll
    for (int nb = 1; nb < 4; ++nb) {
      m4[0] = fmaxf(m4[0], sacc[nb][0]); m4[1] = fmaxf(m4[1], sacc[nb][1]);
      m4[2] = fmaxf(m4[2], sacc[nb][2]); m4[3] = fmaxf(m4[3], sacc[nb][3]);
    }
    float mx = fmaxf(fmaxf(m4[0], m4[1]), fmaxf(m4[2], m4[3]));
    mx = fmaxf(mx, __shfl_xor(mx, 16));
    mx = fmaxf(mx, __shfl_xor(mx, 32));
    const bool skip = __all(mx <= m_run + 64.0f);
    float mnew = skip ? m_run : fmaxf(m_run, mx);
    float mc = mnew * SC;
    float s = 0.f;
#pragma unroll
    for (int nb = 0; nb < 4; ++nb) {
#pragma unroll
      for (int r = 0; r < 4; ++r) {
        float e = __builtin_amdgcn_exp2f(sacc[nb][r] * SC - mc);
        sacc[nb][r] = e; s += e;
      }
    }
    s += __shfl_xor(s, 16);
    s += __shfl_xor(s, 32);
    if (skip) {
      l_run += s;
    } else {
      float resc = __builtin_amdgcn_exp2f((m_run - mnew) * SC);
      l_run = l_run * resc + s;
      m_run = mnew;
      float ro[4];
#pragma unroll
      for (int r = 0; r < 4; ++r) ro[r] = __shfl(resc, g * 4 + r);
#pragma unroll
      for (int nb = 0; nb < 4; ++nb)
#pragma unroll
        for (int r = 0; r < 4; ++r) oacc[nb][r] *= ro[r];
    }
    // ---- PV in two k-halves through the small Ps (16x32/wave) ----
#pragma unroll
    for (int hh2 = 0; hh2 < 2; ++hh2) {
      // pack half hh2: nb = 2*hh2, 2*hh2+1 -> local chunks lc = nb2*4+g
#pragma unroll
      for (int nb2 = 0; nb2 < 2; ++nb2) {
        int nb = 2 * hh2 + nb2;
        union { u16 us[4]; uint2 v; } pk;
#pragma unroll
        for (int r = 0; r < 4; ++r) pk.us[r] = f2bf(sacc[nb][r]);
        int lc = nb2 * 4 + g;
        int sl = (lc >> 1) ^ psl;
        *(uint2*)&psw[l15 * 32 + sl * 8 + (lc & 1) * 4] = pk.v;
      }
      bf16x8 pf = *(const bf16x8*)&psw[l15 * 32 + ((g ^ psl) * 8)];
      __builtin_amdgcn_s_setprio(1);
#pragma unroll
      for (int nb = 0; nb < 4; ++nb) {
        int row = nb * 16 + l15;
        bf16x8 vf = *(const bf16x8*)&Vs[cur][row * 64 + (((hh2 * 4 + g) ^ (row & 7)) * 8)];
        oacc[nb] = __builtin_amdgcn_mfma_f32_16x16x32_bf16(pf, vf, oacc[nb], 0, 0, 0);
      }
      __builtin_amdgcn_s_setprio(0);
    }
    __syncthreads();
    cur ^= 1;
  }
  float linv = 1.f / l_run;
  float io[4];
#pragma unroll
  for (int r = 0; r < 4; ++r) io[r] = __shfl(linv, g * 4 + r);
#pragma unroll
  for (int nb = 0; nb < 4; ++nb) {
#pragma unroll
    for (int r = 0; r < 4; ++r) {
      Om[obase + (size_t)(qstart + wid * 16 + g * 4 + r) * DD + nb * 16 + l15] =
          f2bf(oacc[nb][r] * io[r]);
    }
  }
}

// ---------------------------------------------------------------------------
extern "C" void kernel_launch(void* const* d_in, const int* in_sizes, int n_in,
                              void* d_out, int out_size, void* d_ws, size_t ws_size,
                              hipStream_t stream) {
  const float* x   = (const float*)d_in[0];
  const float* enc = (const float*)d_in[1];
  const float* sa_w[4] = {(const float*)d_in[2], (const float*)d_in[4], (const float*)d_in[6], (const float*)d_in[8]};
  const float* sa_b[4] = {(const float*)d_in[3], (const float*)d_in[5], (const float*)d_in[7], (const float*)d_in[9]};
  const float* ca_w[4] = {(const float*)d_in[10], (const float*)d_in[12], (const float*)d_in[14], (const float*)d_in[16]};
  const float* ca_b[4] = {(const float*)d_in[11], (const float*)d_in[13], (const float*)d_in[15], (const float*)d_in[17]};
  const float* ln_g[3] = {(const float*)d_in[18], (const float*)d_in[20], (const float*)d_in[22]};
  const float* ln_b[3] = {(const float*)d_in[19], (const float*)d_in[21], (const float*)d_in[23]};
  const float* ffw1 = (const float*)d_in[24];
  const float* ffb1 = (const float*)d_in[25];
  const float* ffw2 = (const float*)d_in[26];
  const float* ffb2 = (const float*)d_in[27];

  char* ws = (char*)d_ws;
  size_t o = 0;
  auto take = [&](size_t bytes) {
    void* p = ws + o;
    o += (bytes + 255) & ~(size_t)255;
    return p;
  };
  u16* wqkv  = (u16*)take((size_t)LCOUNT * 1536 * 512 * 2);  // sa q|k|v rows
  u16* wca   = (u16*)take((size_t)LCOUNT * 1536 * 512 * 2);  // ca q|k|v rows
  u16* wosa  = (u16*)take((size_t)LCOUNT * 512 * 512 * 2);
  u16* woca  = (u16*)take((size_t)LCOUNT * 512 * 512 * 2);
  u16* w1t   = (u16*)take((size_t)LCOUNT * 512 * 2048 * 2);
  u16* w2t   = (u16*)take((size_t)LCOUNT * 2048 * 512 * 2);
  float* bqkv = (float*)take((size_t)LCOUNT * 1536 * 4);
  float* bca  = (float*)take((size_t)LCOUNT * 1536 * 4);
  u16* Hb   = (u16*)take((size_t)MM * 512 * 2);
  u16* Eb   = (u16*)take((size_t)MM * 512 * 2);
  u16* QKVb = (u16*)take((size_t)MM * 1536 * 2);
  u16* Ab   = (u16*)take((size_t)MM * 512 * 2);
  u16* Pb   = (u16*)take((size_t)MM * 512 * 2);
  u16* X1b  = (u16*)take((size_t)MM * 512 * 2);
  u16* Yb   = (u16*)take((size_t)MM * 512 * 2);
  u16* Fb   = (u16*)take((size_t)MM * 2048 * 2);
  u16* Vtb  = Fb;  // Vt scratch reuses FFN buffer (dead during attention)

  prep<<<4168, 256, 0, stream>>>(x, enc, Hb, Eb,
                                 sa_b[0], sa_b[1], sa_b[2],
                                 ca_b[0], ca_b[1], ca_b[2], bqkv, bca);
  WtBatch wb;
  wb.src[0] = sa_w[0]; wb.dst[0] = wqkv;              wb.lstr[0] = (size_t)1536 * 512;
  wb.src[1] = sa_w[1]; wb.dst[1] = wqkv + 512 * 512;  wb.lstr[1] = (size_t)1536 * 512;
  wb.src[2] = sa_w[2]; wb.dst[2] = wqkv + 1024 * 512; wb.lstr[2] = (size_t)1536 * 512;
  wb.src[3] = sa_w[3]; wb.dst[3] = wosa;              wb.lstr[3] = (size_t)512 * 512;
  wb.src[4] = ca_w[0]; wb.dst[4] = wca;               wb.lstr[4] = (size_t)1536 * 512;
  wb.src[5] = ca_w[1]; wb.dst[5] = wca + 512 * 512;   wb.lstr[5] = (size_t)1536 * 512;
  wb.src[6] = ca_w[2]; wb.dst[6] = wca + 1024 * 512;  wb.lstr[6] = (size_t)1536 * 512;
  wb.src[7] = ca_w[3]; wb.dst[7] = woca;              wb.lstr[7] = (size_t)512 * 512;
  wtrans8<<<dim3(8, 8, 48), 256, 0, stream>>>(wb);
  wtrans_ffn<<<dim3(256, 12), 256, 0, stream>>>(ffw1, ffw2, w1t, w2t);

  for (int l = 0; l < LCOUNT; ++l) {
    const size_t w512 = (size_t)l * 512 * 512;
    const size_t wff = (size_t)l * 512 * 2048;
    // --- masked self-attention ---
    gemm_bt<128, 128, 64, false, true, false><<<dim3(12, 64), 256, 0, stream>>>(
        Hb, wqkv + (size_t)l * 1536 * 512, bqkv + l * 1536, QKVb, 1536, 512, 1536, Vtb, 1024,
        nullptr, 0, nullptr);
    attn_kernel<true><<<dim3(1024), 256, 0, stream>>>(QKVb, QKVb + 512, Vtb, Ab, 1536);
    gemm_ln<<<dim3(512), 256, 0, stream>>>(Ab, wosa + w512, sa_b[3] + l * 512, Hb,
                                           ln_g[0] + l * 512, ln_b[0] + l * 512,
                                           X1b, nullptr, 512);
    // --- cross-attention: ONE merged GEMM (Q from X1b, K/V from Eb) ---
    gemm_bt<128, 128, 64, false, true, false><<<dim3(12, 64), 256, 0, stream>>>(
        X1b, wca + (size_t)l * 1536 * 512, bca + l * 1536, QKVb, 1536, 512, 1536, Vtb, 1024,
        Eb, 512, nullptr);
    attn_kernel<false><<<dim3(1024), 256, 0, stream>>>(QKVb, QKVb + 512, Vtb, Ab, 1536);
    gemm_ln<<<dim3(512), 256, 0, stream>>>(Ab, woca + w512, ca_b[3] + l * 512, Hb,
                                           ln_g[1] + l * 512, ln_b[1] + l * 512,
                                           Yb, nullptr, 512);
    // --- FFN: FFN2 folds residual(X1b) into epilogue; ln is single-input ---
    gemm_bt<128, 128, 64, true, false, false><<<dim3(16, 64), 256, 0, stream>>>(
        Yb, w1t + wff, ffb1 + l * 2048, Fb, 2048, 512, 2048, nullptr, 0, nullptr, 0, nullptr);
    gemm_bt<64, 128, 128, false, false, true><<<dim3(4, 128), 256, 0, stream>>>(
        Fb, w2t + wff, ffb2 + l * 512, Pb, 512, 2048, 512, nullptr, 0, nullptr, 0, X1b);
    ln_kernel<<<MM / 4, 256, 0, stream>>>(Pb, ln_g[2] + l * 512, ln_b[2] + l * 512, Hb,
                                          (l == LCOUNT - 1) ? (float*)d_out : nullptr);
  }
}

// Round 16
// 1717.645 us; speedup vs baseline: 1.0142x; 1.0142x over previous
//
#include <hip/hip_runtime.h>
#include <stdint.h>

#define LCOUNT 6
#define BB 4
#define SS 2048
#define DD 512
#define HH 8
#define DKK 64
#define FFDIM 2048
#define MM (BB*SS)  // 8192 rows

typedef __attribute__((ext_vector_type(8))) __bf16 bf16x8;
typedef __attribute__((ext_vector_type(4))) float f32x4;
typedef unsigned short u16;

__device__ __forceinline__ u16 f2bf(float f) {
  union { __bf16 h; u16 u; } v; v.h = (__bf16)f; return v.u;
}
__device__ __forceinline__ float bf2f(u16 u) {
  union { uint32_t u; float f; } v; v.u = ((uint32_t)u) << 16;
  return v.f;
}

__device__ __forceinline__ void gload_lds16(const u16* gsrc, u16* ldst) {
  __builtin_amdgcn_global_load_lds((const __attribute__((address_space(1))) char*)gsrc,
                                   (__attribute__((address_space(3))) char*)ldst, 16, 0, 0);
}

// ---------------------------------------------------------------------------
// prep: blocks <4096 convert x/enc fp32->bf16; blocks >=4096 concat biases.
__global__ __launch_bounds__(256)
void prep(const float* __restrict__ x, const float* __restrict__ enc,
          u16* __restrict__ Hb, u16* __restrict__ Eb,
          const float* a0, const float* a1, const float* a2,
          const float* c0, const float* c1, const float* c2,
          float* dqkv, float* dca) {
  if (blockIdx.x < 4096) {
    int i = (blockIdx.x * 256 + threadIdx.x) * 8;
    const int half = MM * 512;
    const float* src = (i < half) ? x : enc;
    u16* dst = (i < half) ? Hb : Eb;
    int j = (i < half) ? i : i - half;
    float4 a = *(const float4*)&src[j];
    float4 b = *(const float4*)&src[j + 4];
    union { u16 us[8]; uint4 v; } pk;
    pk.us[0] = f2bf(a.x); pk.us[1] = f2bf(a.y); pk.us[2] = f2bf(a.z); pk.us[3] = f2bf(a.w);
    pk.us[4] = f2bf(b.x); pk.us[5] = f2bf(b.y); pk.us[6] = f2bf(b.z); pk.us[7] = f2bf(b.w);
    *(uint4*)&dst[j] = pk.v;
  } else {
    int i = (blockIdx.x - 4096) * 256 + threadIdx.x;
    const int half = LCOUNT * 1536;
    if (i >= 2 * half) return;
    bool ca = i >= half;
    int j = ca ? i - half : i;
    int l = j / 1536, cc = j % 1536;
    const float* s = cc < 512 ? (ca ? c0 : a0) : cc < 1024 ? (ca ? c1 : a1) : (ca ? c2 : a2);
    (ca ? dca : dqkv)[j] = s[l * 512 + (cc & 511)];
  }
}

// ---------------------------------------------------------------------------
// Batched 512x512 weight transpose: 8 slots x 6 layers in one dispatch.
struct WtBatch {
  const float* src[8];
  u16* dst[8];
  unsigned long long lstr[8];
};
__global__ __launch_bounds__(256) void wtrans8(WtBatch wb) {
  __shared__ float tile[64 * 65];
  const int z = blockIdx.z;
  const int slot = z / 6, l = z - slot * 6;
  const float* Wl = wb.src[slot] + (size_t)l * 512 * 512;
  u16* Wtl = wb.dst[slot] + (size_t)l * wb.lstr[slot];
  const int n0 = blockIdx.x * 64, k0 = blockIdx.y * 64;
  const int tid = threadIdx.x;
  const int r = tid >> 2, c4 = (tid & 3) * 16;
#pragma unroll
  for (int j = 0; j < 16; j += 4) {
    float4 v = *(const float4*)&Wl[(size_t)(k0 + r) * 512 + n0 + c4 + j];
    tile[r * 65 + c4 + j + 0] = v.x;
    tile[r * 65 + c4 + j + 1] = v.y;
    tile[r * 65 + c4 + j + 2] = v.z;
    tile[r * 65 + c4 + j + 3] = v.w;
  }
  __syncthreads();
  const int nr = tid >> 2, kc = (tid & 3) * 16;
#pragma unroll
  for (int half = 0; half < 2; ++half) {
    union { u16 us[8]; uint4 v; } pk;
#pragma unroll
    for (int e = 0; e < 8; ++e) pk.us[e] = f2bf(tile[(kc + half * 8 + e) * 65 + nr]);
    *(uint4*)&Wtl[(size_t)(n0 + nr) * 512 + k0 + kc + half * 8] = pk.v;
  }
}

// ---------------------------------------------------------------------------
// FFN weight transposes (w1: 512->2048, w2: 2048->512), 12 z-slices.
__global__ __launch_bounds__(256)
void wtrans_ffn(const float* __restrict__ w1, const float* __restrict__ w2,
                u16* __restrict__ w1t, u16* __restrict__ w2t) {
  __shared__ float tile[64 * 65];
  const int z = blockIdx.y;
  const bool is2 = z >= 6;
  const int l = is2 ? z - 6 : z;
  const float* Wl = (is2 ? w2 : w1) + (size_t)l * 512 * 2048;
  u16* Wtl = (is2 ? w2t : w1t) + (size_t)l * 512 * 2048;
  const int K_ = is2 ? 2048 : 512, N_ = is2 ? 512 : 2048;
  const int bx = blockIdx.x;
  const int n0 = is2 ? (bx & 7) * 64 : (bx & 31) * 64;
  const int k0 = is2 ? (bx >> 3) * 64 : (bx >> 5) * 64;
  const int tid = threadIdx.x;
  const int r = tid >> 2, c4 = (tid & 3) * 16;
#pragma unroll
  for (int j = 0; j < 16; j += 4) {
    float4 v = *(const float4*)&Wl[(size_t)(k0 + r) * N_ + n0 + c4 + j];
    tile[r * 65 + c4 + j + 0] = v.x;
    tile[r * 65 + c4 + j + 1] = v.y;
    tile[r * 65 + c4 + j + 2] = v.z;
    tile[r * 65 + c4 + j + 3] = v.w;
  }
  __syncthreads();
  const int nr = tid >> 2, kc = (tid & 3) * 16;
#pragma unroll
  for (int half = 0; half < 2; ++half) {
    union { u16 us[8]; uint4 v; } pk;
#pragma unroll
    for (int e = 0; e < 8; ++e) pk.us[e] = f2bf(tile[(kc + half * 8 + e) * 65 + nr]);
    *(uint4*)&Wtl[(size_t)(n0 + nr) * K_ + k0 + kc + half * 8] = pk.v;
  }
}

// ---------------------------------------------------------------------------
// GEMM: C[M,N] = A[M,K] @ W[K,N] + bias; Wt[N][K]; C row stride CS.
// Template BMT/BNT/BKT; 2x2 waves. Dual-A (bcol >= a2col reads A2). RES:
// epilogue adds residual resid[rowg*DD+col] (FFN2 path). XCD-aware chunked
// swizzle. VT: cols >= vtc0 -> Vt transposed.
template <int BMT, int BNT, int BKT, bool RELU, bool VT, bool RES>
__global__ __launch_bounds__(256)
void gemm_bt(const u16* __restrict__ A, const u16* __restrict__ Bt,
             const float* __restrict__ bias, u16* __restrict__ C,
             int N_, int K_, int CS, u16* __restrict__ vt, int vtc0,
             const u16* __restrict__ A2, int a2col,
             const u16* __restrict__ resid) {
  constexpr int MR = BMT / 32;
  constexpr int NR = BNT / 32;
  constexpr int CH = BKT / 8;
  constexpr int RPR = 2048 / BKT;
  constexpr int KS = BKT / 32;
  __shared__ u16 As[BMT * BKT];
  __shared__ u16 Bs[BNT * BKT];
  const int tid = threadIdx.x;
  const int wid = tid >> 6, lane = tid & 63;
  const int l15 = lane & 15, g = lane >> 4;
  const int wr = wid >> 1, wc = wid & 1;
  const int lrow = (CH == 8) ? (lane >> 3) : (lane >> 4);
  const int lch  = lane & (CH - 1);
  const int wrows = 64 / CH;
  const int lin = blockIdx.x + gridDim.x * blockIdx.y;
  const int nwg = gridDim.x * gridDim.y;
  const int swz = (lin & 7) * (nwg >> 3) + (lin >> 3);
  const int brow = (swz / gridDim.x) * BMT;
  const int bcol = (swz % gridDim.x) * BNT;
  const u16* Ap = (A2 != nullptr && bcol >= a2col) ? A2 : A;

  f32x4 acc[MR][NR];
#pragma unroll
  for (int m = 0; m < MR; ++m)
#pragma unroll
    for (int n = 0; n < NR; ++n) acc[m][n] = (f32x4){0.f, 0.f, 0.f, 0.f};

  for (int kt = 0; kt < K_; kt += BKT) {
#pragma unroll
    for (int r = 0; r < BMT / RPR; ++r) {
      int row = r * RPR + wid * wrows + lrow;
      int slot = lch ^ (row & 7);
      gload_lds16(Ap + (size_t)(brow + row) * K_ + kt + slot * 8,
                  &As[r * 2048 + wid * 512]);
    }
#pragma unroll
    for (int r = 0; r < BNT / RPR; ++r) {
      int row = r * RPR + wid * wrows + lrow;
      int slot = lch ^ (row & 7);
      gload_lds16(Bt + (size_t)(bcol + row) * K_ + kt + slot * 8,
                  &Bs[r * 2048 + wid * 512]);
    }
    __syncthreads();
#pragma unroll
    for (int ks = 0; ks < KS; ++ks) {
      bf16x8 af[MR], bfr[NR];
#pragma unroll
      for (int m = 0; m < MR; ++m) {
        int row = wr * (BMT / 2) + m * 16 + l15;
        int slot = (ks * 4 + g) ^ (row & 7);
        af[m] = *(const bf16x8*)&As[row * BKT + slot * 8];
      }
#pragma unroll
      for (int n = 0; n < NR; ++n) {
        int row = wc * (BNT / 2) + n * 16 + l15;
        int slot = (ks * 4 + g) ^ (row & 7);
        bfr[n] = *(const bf16x8*)&Bs[row * BKT + slot * 8];
      }
#pragma unroll
      for (int m = 0; m < MR; ++m)
#pragma unroll
        for (int n = 0; n < NR; ++n)
          acc[m][n] = __builtin_amdgcn_mfma_f32_16x16x32_bf16(af[m], bfr[n], acc[m][n], 0, 0, 0);
    }
    __syncthreads();
  }
#pragma unroll
  for (int n = 0; n < NR; ++n) {
    int col = bcol + wc * (BNT / 2) + n * 16 + l15;
    float bv = bias ? bias[col] : 0.f;
    if (VT && col >= vtc0) {
      int hh = (col - vtc0) >> 6, dd = (col - vtc0) & 63;
#pragma unroll
      for (int m = 0; m < MR; ++m) {
        int s0g = brow + wr * (BMT / 2) + m * 16 + g * 4;
        int bb = s0g >> 11, ss = s0g & (SS - 1);
        union { u16 us[4]; uint2 v; } pk;
#pragma unroll
        for (int r = 0; r < 4; ++r) pk.us[r] = f2bf(acc[m][n][r] + bv);
        *(uint2*)&vt[(((size_t)(bb * HH + hh)) * DKK + dd) * SS + ss] = pk.v;
      }
    } else {
#pragma unroll
      for (int m = 0; m < MR; ++m) {
#pragma unroll
        for (int r = 0; r < 4; ++r) {
          int rowg = brow + wr * (BMT / 2) + m * 16 + g * 4 + r;
          float v = acc[m][n][r] + bv;
          if (RES) v += bf2f(resid[(size_t)rowg * DD + col]);
          if (RELU) v = fmaxf(v, 0.f);
          C[(size_t)rowg * CS + col] = f2bf(v);
        }
      }
    }
  }
}

// ---------------------------------------------------------------------------
// Fused GEMM + residual + LayerNorm (K=512 only).
__global__ __launch_bounds__(256)
void gemm_ln(const u16* __restrict__ A, const u16* __restrict__ Bt,
             const float* __restrict__ bias, const u16* __restrict__ Res,
             const float* __restrict__ gamma, const float* __restrict__ beta,
             u16* __restrict__ Out, float* __restrict__ Ofp, int K_) {
  __shared__ u16 As[16 * 64];
  __shared__ u16 Bs[512 * 64];
  __shared__ float red[4][16][2];
  const int tid = threadIdx.x;
  const int wid = tid >> 6, lane = tid & 63;
  const int l15 = lane & 15, g = lane >> 4;
  const int lin = blockIdx.x;
  const int swz = (lin & 7) * (gridDim.x >> 3) + (lin >> 3);
  const int brow = swz * 16;
  const int lrow8 = lane >> 3, lch = lane & 7;

  f32x4 acc[8];
#pragma unroll
  for (int n = 0; n < 8; ++n) acc[n] = (f32x4){0.f, 0.f, 0.f, 0.f};

  for (int kt = 0; kt < K_; kt += 64) {
#pragma unroll
    for (int r = 0; r < 17; ++r) {
      int u = wid + 4 * r;
      if (u < 66) {
        if (u < 2) {
          int row = u * 8 + lrow8;
          int slot = lch ^ (row & 7);
          gload_lds16(A + (size_t)(brow + row) * K_ + kt + slot * 8, &As[u * 512]);
        } else {
          int row = (u - 2) * 8 + lrow8;
          int slot = lch ^ (row & 7);
          gload_lds16(Bt + (size_t)row * K_ + kt + slot * 8, &Bs[(u - 2) * 512]);
        }
      }
    }
    __syncthreads();
#pragma unroll
    for (int ks = 0; ks < 2; ++ks) {
      bf16x8 af = *(const bf16x8*)&As[l15 * 64 + (((ks * 4 + g) ^ (l15 & 7)) * 8)];
#pragma unroll
      for (int n = 0; n < 8; ++n) {
        int c = wid * 128 + n * 16 + l15;
        bf16x8 bfr = *(const bf16x8*)&Bs[c * 64 + (((ks * 4 + g) ^ (c & 7)) * 8)];
        acc[n] = __builtin_amdgcn_mfma_f32_16x16x32_bf16(af, bfr, acc[n], 0, 0, 0);
      }
    }
    __syncthreads();
  }
#pragma unroll
  for (int rd = 0; rd < 4; ++rd) {
    int off = rd * 2048 + tid * 8;
    int row = off >> 9, col = off & 511;
    uint4 v = *(const uint4*)&Res[(size_t)(brow + row) * DD + col];
    *(uint4*)&Bs[row * 520 + col] = v;
  }
  __syncthreads();
  float z[8][4];
  float s[4] = {0.f, 0.f, 0.f, 0.f}, s2[4] = {0.f, 0.f, 0.f, 0.f};
#pragma unroll
  for (int n = 0; n < 8; ++n) {
    int col = wid * 128 + n * 16 + l15;
    float bv = bias[col];
#pragma unroll
    for (int r = 0; r < 4; ++r) {
      int rl = g * 4 + r;
      float x = acc[n][r] + bv + bf2f(Bs[rl * 520 + col]);
      z[n][r] = x; s[r] += x; s2[r] += x * x;
    }
  }
#pragma unroll
  for (int r = 0; r < 4; ++r) {
    s[r] += __shfl_xor(s[r], 1);  s2[r] += __shfl_xor(s2[r], 1);
    s[r] += __shfl_xor(s[r], 2);  s2[r] += __shfl_xor(s2[r], 2);
    s[r] += __shfl_xor(s[r], 4);  s2[r] += __shfl_xor(s2[r], 4);
    s[r] += __shfl_xor(s[r], 8);  s2[r] += __shfl_xor(s2[r], 8);
  }
  if (l15 == 0) {
#pragma unroll
    for (int r = 0; r < 4; ++r) {
      red[wid][g * 4 + r][0] = s[r];
      red[wid][g * 4 + r][1] = s2[r];
    }
  }
  __syncthreads();
  float mean[4], rs[4];
#pragma unroll
  for (int r = 0; r < 4; ++r) {
    int rl = g * 4 + r;
    float ts  = red[0][rl][0] + red[1][rl][0] + red[2][rl][0] + red[3][rl][0];
    float ts2 = red[0][rl][1] + red[1][rl][1] + red[2][rl][1] + red[3][rl][1];
    float mn = ts * (1.f / 512.f);
    float var = ts2 * (1.f / 512.f) - mn * mn;
    mean[r] = mn; rs[r] = rsqrtf(var + 1e-5f);
  }
#pragma unroll
  for (int n = 0; n < 8; ++n) {
    int col = wid * 128 + n * 16 + l15;
    float gm = gamma[col], bt = beta[col];
#pragma unroll
    for (int r = 0; r < 4; ++r) {
      int rowg = brow + g * 4 + r;
      float o = (z[n][r] - mean[r]) * rs[r] * gm + bt;
      Out[(size_t)rowg * DD + col] = f2bf(o);
      if (Ofp) Ofp[(size_t)rowg * DD + col] = o;
    }
  }
}

// ---------------------------------------------------------------------------
// LayerNorm(a) * g + beta (residual already folded into a); one wave per row.
__global__ __launch_bounds__(256)
void ln_kernel(const u16* __restrict__ A,
               const float* __restrict__ gamma, const float* __restrict__ beta,
               u16* __restrict__ out_bf, float* __restrict__ out_f32) {
  const int row = blockIdx.x * 4 + (threadIdx.x >> 6);
  const int lane = threadIdx.x & 63;
  uint4 av = *(const uint4*)&A[(size_t)row * DD + lane * 8];
  const u16* au = (const u16*)&av;
  float z[8], s = 0.f, s2 = 0.f;
#pragma unroll
  for (int j = 0; j < 8; ++j) {
    float x = bf2f(au[j]);
    z[j] = x; s += x; s2 += x * x;
  }
#pragma unroll
  for (int off = 1; off < 64; off <<= 1) {
    s += __shfl_xor(s, off);
    s2 += __shfl_xor(s2, off);
  }
  float mean = s * (1.f / 512.f);
  float var = s2 * (1.f / 512.f) - mean * mean;
  float rs = rsqrtf(var + 1e-5f);
  union { u16 us[8]; uint4 v; } pk;
#pragma unroll
  for (int j = 0; j < 8; ++j) {
    float o = (z[j] - mean) * rs * gamma[lane * 8 + j] + beta[lane * 8 + j];
    pk.us[j] = f2bf(o);
    if (out_f32) out_f32[(size_t)row * DD + lane * 8 + j] = o;
  }
  *(uint4*)&out_bf[(size_t)row * DD + lane * 8] = pk.v;
}

// ---------------------------------------------------------------------------
// Flash attention, swapped-QK^T (r6/r9-proven structure, FROZEN).
template <bool CAUSAL>
__global__ __launch_bounds__(256, 4)
void attn_kernel(const u16* __restrict__ Qm, const u16* __restrict__ Km,
                 const u16* __restrict__ Vt, u16* __restrict__ Om, int qks) {
  __shared__ u16 Ks[2][64 * 64];
  __shared__ u16 Vs[2][64 * 64];
  __shared__ u16 Ps[4][16 * 64];
  const int lin = blockIdx.x;
  const int bh = (lin & 7) * 4 + ((lin >> 3) >> 5);
  const int qc = (lin >> 3) & 31;
  const int qb = (qc & 1) ? (31 - (qc >> 1)) : (qc >> 1);
  const int h = bh & 7, b = bh >> 3;
  const int tid = threadIdx.x, wid = tid >> 6, lane = tid & 63;
  const int l15 = lane & 15, g = lane >> 4;
  const int qstart = qb * 64;
  const size_t qbase = ((size_t)b * SS) * qks + h * DKK;
  const size_t vtbase = (size_t)(b * HH + h) * DKK * SS;
  const size_t obase = ((size_t)b * SS) * DD + h * DKK;
  u16* psw = &Ps[wid][0];
  const int srow = wid * 8 + (lane >> 3);
  const int sslot = lane & 7;
  const int qg = qstart + wid * 16 + l15;
  const int pswz = (l15 & 7) << 1;
  const float SC = 0.18033688f;  // 0.125 * log2(e)

  const u16* kp = Km + qbase;
  const u16* vp = Vt + vtbase;

  bf16x8 qf[2];
#pragma unroll
  for (int ks = 0; ks < 2; ++ks)
    qf[ks] = *(const bf16x8*)&Qm[qbase + (size_t)qg * qks + ks * 32 + g * 8];

  f32x4 oacc[4];
#pragma unroll
  for (int nb = 0; nb < 4; ++nb) oacc[nb] = (f32x4){0.f, 0.f, 0.f, 0.f};
  float m_run = -3.0e38f, l_run = 0.f;

  const int T = CAUSAL ? (qb + 1) : (SS / 64);

#pragma unroll
  for (int r = 0; r < 2; ++r) {
    int row = r * 32 + srow;
    int slot = sslot ^ (row & 7);
    gload_lds16(kp + (size_t)row * qks + slot * 8, &Ks[0][r * 2048 + wid * 512]);
    gload_lds16(vp + (size_t)row * SS + slot * 8, &Vs[0][r * 2048 + wid * 512]);
  }
  __syncthreads();

  int cur = 0;
  for (int t = 0; t < T; ++t) {
    const int kstart = t * 64;
    if (t + 1 < T) {
#pragma unroll
      for (int r = 0; r < 2; ++r) {
        int row = r * 32 + srow;
        int slot = sslot ^ (row & 7);
        gload_lds16(kp + (size_t)(kstart + 64 + row) * qks + slot * 8,
                    &Ks[cur ^ 1][r * 2048 + wid * 512]);
        gload_lds16(vp + (size_t)row * SS + kstart + 64 + slot * 8,
                    &Vs[cur ^ 1][r * 2048 + wid * 512]);
      }
    }
    f32x4 sacc[4];
#pragma unroll
    for (int nb = 0; nb < 4; ++nb) sacc[nb] = (f32x4){0.f, 0.f, 0.f, 0.f};
    __builtin_amdgcn_s_setprio(1);
#pragma unroll
    for (int nb = 0; nb < 4; ++nb) {
      int row = nb * 16 + l15;
#pragma unroll
      for (int ks = 0; ks < 2; ++ks) {
        bf16x8 kf = *(const bf16x8*)&Ks[cur][row * 64 + (((ks * 4 + g) ^ (row & 7)) * 8)];
        sacc[nb] = __builtin_amdgcn_mfma_f32_16x16x32_bf16(kf, qf[ks], sacc[nb], 0, 0, 0);
      }
    }
    __builtin_amdgcn_s_setprio(0);
    if (CAUSAL && t == T - 1) {
#pragma unroll
      for (int nb = 0; nb < 4; ++nb)
#pragma unroll
        for (int r = 0; r < 4; ++r)
          if ((kstart + nb * 16 + g * 4 + r) > qg) sacc[nb][r] = -3.0e38f;
    }
    f32x4 m4 = sacc[0];
#pragma unroll
    for (int nb = 1; nb < 4; ++nb) {
      m4[0] = fmaxf(m4[0], sacc[nb][0]); m4[1] = fmaxf(m4[1], sacc[nb][1]);
      m4[2] = fmaxf(m4[2], sacc[nb][2]); m4[3] = fmaxf(m4[3], sacc[nb][3]);
    }
    float mx = fmaxf(fmaxf(m4[0], m4[1]), fmaxf(m4[2], m4[3]));
    mx = fmaxf(mx, __shfl_xor(mx, 16));
    mx = fmaxf(mx, __shfl_xor(mx, 32));
    const bool skip = __all(mx <= m_run + 64.0f);
    float mnew = skip ? m_run : fmaxf(m_run, mx);
    float mc = mnew * SC;
    float s = 0.f;
#pragma unroll
    for (int nb = 0; nb < 4; ++nb) {
#pragma unroll
      for (int r = 0; r < 4; ++r) {
        float e = __builtin_amdgcn_exp2f(sacc[nb][r] * SC - mc);
        sacc[nb][r] = e; s += e;
      }
    }
    s += __shfl_xor(s, 16);
    s += __shfl_xor(s, 32);
    if (skip) {
      l_run += s;
    } else {
      float resc = __builtin_amdgcn_exp2f((m_run - mnew) * SC);
      l_run = l_run * resc + s;
      m_run = mnew;
      float ro[4];
#pragma unroll
      for (int r = 0; r < 4; ++r) ro[r] = __shfl(resc, g * 4 + r);
#pragma unroll
      for (int nb = 0; nb < 4; ++nb)
#pragma unroll
        for (int r = 0; r < 4; ++r) oacc[nb][r] *= ro[r];
    }
#pragma unroll
    for (int nb = 0; nb < 4; ++nb) {
      union { u16 us[4]; uint2 v; } pk;
#pragma unroll
      for (int r = 0; r < 4; ++r) pk.us[r] = f2bf(sacc[nb][r]);
      int cp = (nb * 4 + g) ^ pswz;
      *(uint2*)&psw[l15 * 64 + cp * 4] = pk.v;
    }
    bf16x8 pf[2];
#pragma unroll
    for (int ks = 0; ks < 2; ++ks) {
      int cp0 = (8 * ks + 2 * g) ^ pswz;
      pf[ks] = *(const bf16x8*)&psw[l15 * 64 + cp0 * 4];
    }
    __builtin_amdgcn_s_setprio(1);
#pragma unroll
    for (int nb = 0; nb < 4; ++nb) {
      int row = nb * 16 + l15;
#pragma unroll
      for (int ks = 0; ks < 2; ++ks) {
        bf16x8 vf = *(const bf16x8*)&Vs[cur][row * 64 + (((ks * 4 + g) ^ (row & 7)) * 8)];
        oacc[nb] = __builtin_amdgcn_mfma_f32_16x16x32_bf16(pf[ks], vf, oacc[nb], 0, 0, 0);
      }
    }
    __builtin_amdgcn_s_setprio(0);
    __syncthreads();
    cur ^= 1;
  }
  float linv = 1.f / l_run;
  float io[4];
#pragma unroll
  for (int r = 0; r < 4; ++r) io[r] = __shfl(linv, g * 4 + r);
#pragma unroll
  for (int nb = 0; nb < 4; ++nb) {
#pragma unroll
    for (int r = 0; r < 4; ++r) {
      Om[obase + (size_t)(qstart + wid * 16 + g * 4 + r) * DD + nb * 16 + l15] =
          f2bf(oacc[nb][r] * io[r]);
    }
  }
}

// ---------------------------------------------------------------------------
extern "C" void kernel_launch(void* const* d_in, const int* in_sizes, int n_in,
                              void* d_out, int out_size, void* d_ws, size_t ws_size,
                              hipStream_t stream) {
  const float* x   = (const float*)d_in[0];
  const float* enc = (const float*)d_in[1];
  const float* sa_w[4] = {(const float*)d_in[2], (const float*)d_in[4], (const float*)d_in[6], (const float*)d_in[8]};
  const float* sa_b[4] = {(const float*)d_in[3], (const float*)d_in[5], (const float*)d_in[7], (const float*)d_in[9]};
  const float* ca_w[4] = {(const float*)d_in[10], (const float*)d_in[12], (const float*)d_in[14], (const float*)d_in[16]};
  const float* ca_b[4] = {(const float*)d_in[11], (const float*)d_in[13], (const float*)d_in[15], (const float*)d_in[17]};
  const float* ln_g[3] = {(const float*)d_in[18], (const float*)d_in[20], (const float*)d_in[22]};
  const float* ln_b[3] = {(const float*)d_in[19], (const float*)d_in[21], (const float*)d_in[23]};
  const float* ffw1 = (const float*)d_in[24];
  const float* ffb1 = (const float*)d_in[25];
  const float* ffw2 = (const float*)d_in[26];
  const float* ffb2 = (const float*)d_in[27];

  char* ws = (char*)d_ws;
  size_t o = 0;
  auto take = [&](size_t bytes) {
    void* p = ws + o;
    o += (bytes + 255) & ~(size_t)255;
    return p;
  };
  u16* wqkv  = (u16*)take((size_t)LCOUNT * 1536 * 512 * 2);  // sa q|k|v rows
  u16* wca   = (u16*)take((size_t)LCOUNT * 1536 * 512 * 2);  // ca q|k|v rows
  u16* wosa  = (u16*)take((size_t)LCOUNT * 512 * 512 * 2);
  u16* woca  = (u16*)take((size_t)LCOUNT * 512 * 512 * 2);
  u16* w1t   = (u16*)take((size_t)LCOUNT * 512 * 2048 * 2);
  u16* w2t   = (u16*)take((size_t)LCOUNT * 2048 * 512 * 2);
  float* bqkv = (float*)take((size_t)LCOUNT * 1536 * 4);
  float* bca  = (float*)take((size_t)LCOUNT * 1536 * 4);
  u16* Hb   = (u16*)take((size_t)MM * 512 * 2);
  u16* Eb   = (u16*)take((size_t)MM * 512 * 2);
  u16* QKVb = (u16*)take((size_t)MM * 1536 * 2);
  u16* Ab   = (u16*)take((size_t)MM * 512 * 2);
  u16* Pb   = (u16*)take((size_t)MM * 512 * 2);
  u16* X1b  = (u16*)take((size_t)MM * 512 * 2);
  u16* Yb   = (u16*)take((size_t)MM * 512 * 2);
  u16* Fb   = (u16*)take((size_t)MM * 2048 * 2);
  u16* Vtb  = Fb;  // Vt scratch reuses FFN buffer (dead during attention)

  prep<<<4168, 256, 0, stream>>>(x, enc, Hb, Eb,
                                 sa_b[0], sa_b[1], sa_b[2],
                                 ca_b[0], ca_b[1], ca_b[2], bqkv, bca);
  WtBatch wb;
  wb.src[0] = sa_w[0]; wb.dst[0] = wqkv;              wb.lstr[0] = (size_t)1536 * 512;
  wb.src[1] = sa_w[1]; wb.dst[1] = wqkv + 512 * 512;  wb.lstr[1] = (size_t)1536 * 512;
  wb.src[2] = sa_w[2]; wb.dst[2] = wqkv + 1024 * 512; wb.lstr[2] = (size_t)1536 * 512;
  wb.src[3] = sa_w[3]; wb.dst[3] = wosa;              wb.lstr[3] = (size_t)512 * 512;
  wb.src[4] = ca_w[0]; wb.dst[4] = wca;               wb.lstr[4] = (size_t)1536 * 512;
  wb.src[5] = ca_w[1]; wb.dst[5] = wca + 512 * 512;   wb.lstr[5] = (size_t)1536 * 512;
  wb.src[6] = ca_w[2]; wb.dst[6] = wca + 1024 * 512;  wb.lstr[6] = (size_t)1536 * 512;
  wb.src[7] = ca_w[3]; wb.dst[7] = woca;              wb.lstr[7] = (size_t)512 * 512;
  wtrans8<<<dim3(8, 8, 48), 256, 0, stream>>>(wb);
  wtrans_ffn<<<dim3(256, 12), 256, 0, stream>>>(ffw1, ffw2, w1t, w2t);

  for (int l = 0; l < LCOUNT; ++l) {
    const size_t w512 = (size_t)l * 512 * 512;
    const size_t wff = (size_t)l * 512 * 2048;
    // --- masked self-attention ---
    gemm_bt<128, 128, 64, false, true, false><<<dim3(12, 64), 256, 0, stream>>>(
        Hb, wqkv + (size_t)l * 1536 * 512, bqkv + l * 1536, QKVb, 1536, 512, 1536, Vtb, 1024,
        nullptr, 0, nullptr);
    attn_kernel<true><<<dim3(1024), 256, 0, stream>>>(QKVb, QKVb + 512, Vtb, Ab, 1536);
    gemm_ln<<<dim3(512), 256, 0, stream>>>(Ab, wosa + w512, sa_b[3] + l * 512, Hb,
                                           ln_g[0] + l * 512, ln_b[0] + l * 512,
                                           X1b, nullptr, 512);
    // --- cross-attention: ONE merged GEMM (Q from X1b, K/V from Eb) ---
    gemm_bt<128, 128, 64, false, true, false><<<dim3(12, 64), 256, 0, stream>>>(
        X1b, wca + (size_t)l * 1536 * 512, bca + l * 1536, QKVb, 1536, 512, 1536, Vtb, 1024,
        Eb, 512, nullptr);
    attn_kernel<false><<<dim3(1024), 256, 0, stream>>>(QKVb, QKVb + 512, Vtb, Ab, 1536);
    gemm_ln<<<dim3(512), 256, 0, stream>>>(Ab, woca + w512, ca_b[3] + l * 512, Hb,
                                           ln_g[1] + l * 512, ln_b[1] + l * 512,
                                           Yb, nullptr, 512);
    // --- FFN: FFN2 folds residual(X1b) into epilogue; ln is single-input ---
    gemm_bt<128, 128, 64, true, false, false><<<dim3(16, 64), 256, 0, stream>>>(
        Yb, w1t + wff, ffb1 + l * 2048, Fb, 2048, 512, 2048, nullptr, 0, nullptr, 0, nullptr);
    gemm_bt<64, 128, 128, false, false, true><<<dim3(4, 128), 256, 0, stream>>>(
        Fb, w2t + wff, ffb2 + l * 512, Pb, 512, 2048, 512, nullptr, 0, nullptr, 0, X1b);
    ln_kernel<<<MM / 4, 256, 0, stream>>>(Pb, ln_g[2] + l * 512, ln_b[2] + l * 512, Hb,
                                          (l == LCOUNT - 1) ? (float*)d_out : nullptr);
  }
}